// Round 10
// baseline (187.878 us; speedup 1.0000x reference)
//
#include <hip/hip_runtime.h>
#include <hip/hip_bf16.h>

#define G_ 8
#define GIN_ 256
#define GOUT_ 256
#define NROWS_ 8192
#define LDX_ 2048   // = G_*GIN_ = row stride of x and out

typedef __attribute__((ext_vector_type(4))) float f32x4;
typedef __attribute__((ext_vector_type(8))) short bf16x8;

// LDS-only barrier: no vmcnt(0) drain (global ops stay in flight).
__device__ __forceinline__ void lds_barrier() {
    asm volatile("s_waitcnt lgkmcnt(0)\n\ts_barrier" ::: "memory");
}

// ---------------------------------------------------------------------------
// Prep: W [G][GIN=k 256][GOUT=col 256] f32 -> WtB fragment-tiled bf16:
//   granule(g, c, cb, c16, quad) = W[g][k = c*32+quad*8 .. +8][col = cb*16+c16]
//   element offset = g*65536 + (c*16+cb)*512 + c16*32 + quad*8
// A wave's B-frag load (16 cols x 4 quads x 16B) is ONE contiguous 1 KB.
// (unchanged — harness-verified)
// ---------------------------------------------------------------------------
__global__ __launch_bounds__(256) void wprep_kernel(const float* __restrict__ W,
                                                    __hip_bfloat16* __restrict__ Wt) {
    __shared__ float tile[64][65];   // +1 pad
    const int bid = blockIdx.x;
    const int g  = bid >> 4;
    const int kt = (bid >> 2) & 3;   // k-tile (64 wide)
    const int ct = bid & 3;          // col-tile (64 wide)
    const float* Wg = W + g * (GIN_ * GOUT_);
    __hip_bfloat16* Wo = Wt + (size_t)g * (GIN_ * GOUT_);
    const int lane_o = threadIdx.x & 63;   // col within tile
    const int sub    = threadIdx.x >> 6;   // 0..3
#pragma unroll
    for (int r = 0; r < 16; ++r) {
        int i = r * 4 + sub;               // k within tile
        tile[i][lane_o] = Wg[(kt * 64 + i) * GOUT_ + ct * 64 + lane_o];
    }
    __syncthreads();
    const int col = threadIdx.x & 63;
    const int kgb = threadIdx.x >> 6;      // 0..3
#pragma unroll
    for (int h = 0; h < 2; ++h) {
        const int kg    = kgb + h * 4;     // 0..7: granule-of-8k in 64-k tile
        const int kglob = kt * 64 + kg * 8;
        const int c     = kglob >> 5;      // k-chunk 0..7
        const int quad  = (kglob >> 3) & 3;
        const int colg  = ct * 64 + col;
        const int cb    = colg >> 4;
        const int c16   = colg & 15;
        union { __hip_bfloat16 hh[8]; bf16x8 v; } cv;
#pragma unroll
        for (int j = 0; j < 8; ++j)
            cv.hh[j] = __float2bfloat16(tile[kg * 8 + j][col]);
        *(bf16x8*)(Wo + (size_t)(c * 16 + cb) * 512 + c16 * 32 + quad * 8) = cv.v;
    }
}

// ---------------------------------------------------------------------------
// Main fused kernel — CONTIGUOUS HBM STREAMS (R10).
//  R0-R9: nine structures (occupancy 30-78%, VGPR 24-64, DMA staging,
//  counted-vmcnt pipeline, dwordx4 stores) ALL pin at ~42 µs = 2.4 TB/s,
//  while fillBufferAligned (contiguous) does 6.5 TB/s in the same trace.
//  The one invariant: g=bid&7 column-partitioning makes BOTH HBM streams
//  1KB-slices at 8KB stride — a DRAM row-activation-bound pattern (~2.5x
//  efficiency loss = the unexplained 2.2x over the ~20 µs traffic floor).
//  Fix: partition by ROWS ONLY.
//   - Block = 16 full rows x 2048 cols (grid 512). x read = 128 KB
//     CONTIGUOUS (each staging instr = one full 8 KB row); out write =
//     full rows. Both streams DRAM-sequential.
//   - Wave w computes group w: 16 rows x 256 cols; W stream = Wt[w]
//     (128 KB) from L2 once per block (contiguous 1 KB frags, L2-hot
//     everywhere since Wt = 1 MiB < 4 MiB/XCD).
//   - x staged bf16 row-major [16][2048] in LDS (64 KB), granule swizzle
//     phys = (gk&~7)|((gk&7)^(row&7)); write order rotated per lane to
//     stay at the b64 bank floor; A-frag read hits the b128 floor.
//   - 2 col-passes of 128 cols (acc[8] = 32 VGPRs/pass); swapped-operand
//     MFMA (transposed C) + f32x4 stores from R8. Numerics identical.
// ---------------------------------------------------------------------------
__global__ __launch_bounds__(512, 4) void gkan_kernel(const float* __restrict__ x,
                                                      const __hip_bfloat16* __restrict__ Wt,
                                                      const float* __restrict__ bias,
                                                      const float* __restrict__ pc,
                                                      const float* __restrict__ qc,
                                                      float* __restrict__ out) {
    __shared__ __align__(16) __hip_bfloat16 As[16 * 2048];   // 64 KB

    const int bid  = blockIdx.x;
    const int row0 = bid * 16;

    const int t    = threadIdx.x;
    const int w    = t >> 6;             // wave 0..7 == group
    const int lane = t & 63;
    const int lm   = lane & 15;
    const int q    = lane >> 4;

    // ---- staging: 16 instrs, each = ONE FULL 8 KB ROW (perfectly coalesced,
    //      DRAM-sequential). Thread t owns cols [t*4, t*4+4) of every row. ----
    {
        const float* xb = x + (size_t)row0 * LDX_ + t * 4;
        f32x4 v[16];
#pragma unroll
        for (int r = 0; r < 16; ++r)
            v[r] = *(const f32x4*)(xb + (size_t)r * LDX_);

        const int gk   = t >> 1;         // 16B granule 0..255 within a row
        const int half = t & 1;          // 8B half within granule
#pragma unroll
        for (int i = 0; i < 16; ++i) {
            const int r = i ^ (gk & 7);  // rotate write order: bank-floor spread
            union { __hip_bfloat16 h[4]; uint2 u2; } cv;
            cv.h[0] = __float2bfloat16(v[r].x);
            cv.h[1] = __float2bfloat16(v[r].y);
            cv.h[2] = __float2bfloat16(v[r].z);
            cv.h[3] = __float2bfloat16(v[r].w);
            const int phys = (gk & ~7) | ((gk & 7) ^ (r & 7));
            *(uint2*)((char*)As + r * 4096 + phys * 16 + half * 8) = cv.u2;
        }
    }
    lds_barrier();

    // ---- per-group consts (g == wave) ----
    const float p0 = pc[w * 4 + 0], p1 = pc[w * 4 + 1];
    const float p2 = pc[w * 4 + 2], p3 = pc[w * 4 + 3];
    const float q0 = qc[w * 3 + 0], q1 = qc[w * 3 + 1], q2 = qc[w * 3 + 2];

    const char* ab = (const char*)As + lm * 4096 + w * 512;   // row lm, group w

    // ---- 2 col-passes of 128 cols each ----
#pragma unroll 1
    for (int p = 0; p < 2; ++p) {
        f32x4 acc[8] = {};
        const __hip_bfloat16* bp = Wt + (size_t)w * (GIN_ * GOUT_)
                                      + (size_t)(p * 8) * 512 + lm * 32 + q * 8;
#pragma unroll 1
        for (int c = 0; c < 8; ++c) {
            // A frag: row lm, k-granule gg = c*4+q (swizzled), 8 bf16
            const int gg   = c * 4 + q;
            const int phys = (gg & 24) | ((gg & 7) ^ (lm & 7));
            const bf16x8 af = *(const bf16x8*)(ab + phys * 16);
            // 8 B-frags (each wave-instr = contiguous 1 KB from L2) + 8 MFMA
            const __hip_bfloat16* bc = bp + (size_t)c * (16 * 512);
#pragma unroll
            for (int nt = 0; nt < 8; ++nt) {
                const bf16x8 bf = *(const bf16x8*)(bc + nt * 512);
                acc[nt] = __builtin_amdgcn_mfma_f32_16x16x32_bf16(bf, af, acc[nt], 0, 0, 0);
            }
        }

        // ---- epilogue pass p: transposed-C (lane lm = out-row, reg r = 4
        //      consecutive cols), bias + rational, f32x4 stores ----
        const int colb = w * GOUT_ + p * 128;
#pragma unroll
        for (int nt = 0; nt < 8; ++nt) {
            const int col0 = colb + nt * 16 + q * 4;
            const f32x4 bb4 = *(const f32x4*)(bias + col0);
            f32x4 o;
#pragma unroll
            for (int r = 0; r < 4; ++r) {
                const float y   = acc[nt][r] + bb4[r];
                const float num = p0 + y * (p1 + y * (p2 + y * p3));
                const float den = 1.0f + fabsf(y * (q0 + y * (q1 + y * q2)));
                o[r] = num * __builtin_amdgcn_rcpf(den);
            }
            *(f32x4*)(out + (size_t)(row0 + lm) * LDX_ + col0) = o;
        }
    }
}

extern "C" void kernel_launch(void* const* d_in, const int* in_sizes, int n_in,
                              void* d_out, int out_size, void* d_ws, size_t ws_size,
                              hipStream_t stream) {
    const float* x = (const float*)d_in[0];
    const float* W = (const float*)d_in[1];
    const float* b = (const float*)d_in[2];
    const float* p = (const float*)d_in[3];
    const float* q = (const float*)d_in[4];
    float* out = (float*)d_out;

    __hip_bfloat16* Wt = (__hip_bfloat16*)d_ws;   // 1 MiB fragment-tiled bf16 W

    wprep_kernel<<<128, 256, 0, stream>>>(W, Wt);
    gkan_kernel<<<512, 512, 0, stream>>>(x, Wt, b, p, q, out);
}

// Round 11
// 135.091 us; speedup vs baseline: 1.3907x; 1.3907x over previous
//
#include <hip/hip_runtime.h>
#include <hip/hip_bf16.h>

#define G_ 8
#define GIN_ 256
#define GOUT_ 256
#define NROWS_ 8192
#define LDX_ 2048   // = G_*GIN_ = row stride of x and out

typedef __attribute__((ext_vector_type(4))) float f32x4;
typedef __attribute__((ext_vector_type(8))) short bf16x8;

// ---------------------------------------------------------------------------
// Prep: W [G][GIN=k 256][GOUT=col 256] f32 -> WtB fragment-tiled bf16:
//   granule(g, c, cb, c16, quad) = W[g][k = c*32+quad*8 .. +8][col = cb*16+c16]
//   element offset = g*65536 + (c*16+cb)*512 + c16*32 + quad*8
// A wave's B-frag load (16 cols x 4 quads x 16B) is ONE contiguous 1 KB.
// (unchanged — harness-verified)
// ---------------------------------------------------------------------------
__global__ __launch_bounds__(256) void wprep_kernel(const float* __restrict__ W,
                                                    __hip_bfloat16* __restrict__ Wt) {
    __shared__ float tile[64][65];   // +1 pad
    const int bid = blockIdx.x;
    const int g  = bid >> 4;
    const int kt = (bid >> 2) & 3;   // k-tile (64 wide)
    const int ct = bid & 3;          // col-tile (64 wide)
    const float* Wg = W + g * (GIN_ * GOUT_);
    __hip_bfloat16* Wo = Wt + (size_t)g * (GIN_ * GOUT_);
    const int lane_o = threadIdx.x & 63;   // col within tile
    const int sub    = threadIdx.x >> 6;   // 0..3
#pragma unroll
    for (int r = 0; r < 16; ++r) {
        int i = r * 4 + sub;               // k within tile
        tile[i][lane_o] = Wg[(kt * 64 + i) * GOUT_ + ct * 64 + lane_o];
    }
    __syncthreads();
    const int col = threadIdx.x & 63;
    const int kgb = threadIdx.x >> 6;      // 0..3
#pragma unroll
    for (int h = 0; h < 2; ++h) {
        const int kg    = kgb + h * 4;     // 0..7: granule-of-8k in 64-k tile
        const int kglob = kt * 64 + kg * 8;
        const int c     = kglob >> 5;      // k-chunk 0..7
        const int quad  = (kglob >> 3) & 3;
        const int colg  = ct * 64 + col;
        const int cb    = colg >> 4;
        const int c16   = colg & 15;
        union { __hip_bfloat16 hh[8]; bf16x8 v; } cv;
#pragma unroll
        for (int j = 0; j < 8; ++j)
            cv.hh[j] = __float2bfloat16(tile[kg * 8 + j][col]);
        *(bf16x8*)(Wo + (size_t)(c * 16 + cb) * 512 + c16 * 32 + quad * 8) = cv.v;
    }
}

__device__ __forceinline__ bf16x8 cvt8(const f32x4 a, const f32x4 b) {
    union { __hip_bfloat16 h[8]; bf16x8 v; } u;
    u.h[0] = __float2bfloat16(a.x); u.h[1] = __float2bfloat16(a.y);
    u.h[2] = __float2bfloat16(a.z); u.h[3] = __float2bfloat16(a.w);
    u.h[4] = __float2bfloat16(b.x); u.h[5] = __float2bfloat16(b.y);
    u.h[6] = __float2bfloat16(b.z); u.h[7] = __float2bfloat16(b.w);
    return u.v;
}

// ---------------------------------------------------------------------------
// Main fused kernel — R9 + NON-TEMPORAL STORES (R11).
//  R10 post-mortem: row-contiguous streams made it WORSE (2x traffic: lost
//  x's cross-iteration L3 residency + write amplification) — rate pinned at
//  ~2.1-2.6 TB/s regardless. Surviving mechanism across ALL ten variants:
//  65 MB of CACHED stores per dispatch allocate in L2/L3, competing with
//  the x read stream at the L3/fabric boundary (~3.1 TB/s total there) and
//  evicting x (FETCH = 33 MB = x half re-fetched every iteration), while
//  fillBufferAligned's streaming stores do 6.5 TB/s.
//  One variable vs R9: epilogue stores -> __builtin_nontemporal_store
//  (gfx950 'nt': no cache allocation). Predicted signature: FETCH 33 -> <10
//  MB (x stays L3-resident), dur 41 -> ~30-34 µs.
//  Everything else == R9: counted-vmcnt 2-phase pipeline, DMA x-staging,
//  B-preload in regs, swapped-operand MFMA (transposed C), dwordx4 stores.
// Grid: 8 g x 256 rowblocks = 2048 blocks; bid&7 = g keeps Wt[g] XCD-local.
// ---------------------------------------------------------------------------
__global__ __launch_bounds__(512, 6) void gkan_kernel(const float* __restrict__ x,
                                                      const __hip_bfloat16* __restrict__ Wt,
                                                      const float* __restrict__ bias,
                                                      const float* __restrict__ pc,
                                                      const float* __restrict__ qc,
                                                      float* __restrict__ out) {
    __shared__ __align__(16) float As[32 * 256];   // 32 KB: [half][row][512B]

    const int bid  = blockIdx.x;
    const int g    = bid & 7;
    const int row0 = (bid >> 3) * 32;

    const int t    = threadIdx.x;
    const int wave = t >> 6;             // 0..7 -> cols [wave*32, +32)
    const int lane = t & 63;
    const int lm   = lane & 15;
    const int q    = lane >> 4;

    // ---- B preload: chunks 0-3 (8 loads, OLDEST vmem) ----
    const __hip_bfloat16* bp = Wt + (size_t)g * (GIN_ * GOUT_)
                                  + (wave * 2) * 512 + lm * 32 + q * 8;
    bf16x8 B0[4], B1[4];
#pragma unroll
    for (int c = 0; c < 4; ++c) {
        B0[c] = *(const bf16x8*)(bp + (size_t)c * (16 * 512));
        B1[c] = *(const bf16x8*)(bp + (size_t)c * (16 * 512) + 512);
    }

    // ---- x slab DMA: half0 (2 instrs), then half1 (2 instrs) ----
    // instr (h,j): LDS dest = h*16384 + j*8192 + t*16 (linear)
    //   -> row = j*16 + (t>>5), in-half granule gg = t&31
    //   src granule = h*32 + (gg&24) + ((gg&7) ^ (row&7))   [inverse swizzle]
    {
        const float* xrow = x + (size_t)row0 * LDX_ + g * GIN_;
        const int rw  = t >> 5;          // 0..15
        const int g8  = t & 7;
        const int ghi = t & 24;
#pragma unroll
        for (int h = 0; h < 2; ++h)
#pragma unroll
            for (int j = 0; j < 2; ++j) {
                const int row  = j * 16 + rw;
                const int gsrc = h * 32 + ghi + (g8 ^ (row & 7));
                const float* src = xrow + (size_t)row * LDX_ + gsrc * 4;
                __builtin_amdgcn_global_load_lds(
                    (const __attribute__((address_space(1))) void*)src,
                    (__attribute__((address_space(3))) void*)
                        ((char*)As + h * 16384 + j * 8192 + t * 16),
                    16, 0, 0);
            }
    }

    // ---- phase 0 gate: B0-3 + half0 landed; half1 (2 ops) stays in flight
    asm volatile("s_waitcnt vmcnt(2)\n\ts_barrier" ::: "memory");

    // ---- phase 0: chunks 0-3 from LDS half0 ----
    f32x4 acc[2][2] = {};   // acc[mt][nt], swapped-operand (transposed C)
#pragma unroll
    for (int c = 0; c < 4; ++c) {
        bf16x8 af[2];
#pragma unroll
        for (int mt = 0; mt < 2; ++mt) {
            const int rr  = mt * 16 + lm;
            const int gg0 = c * 8 + ((q * 2)     ^ (lm & 7));
            const int gg1 = c * 8 + ((q * 2 + 1) ^ (lm & 7));
            const f32x4 lo = *(const f32x4*)((const char*)As + rr * 512 + gg0 * 16);
            const f32x4 hi = *(const f32x4*)((const char*)As + rr * 512 + gg1 * 16);
            af[mt] = cvt8(lo, hi);
        }
        acc[0][0] = __builtin_amdgcn_mfma_f32_16x16x32_bf16(B0[c], af[0], acc[0][0], 0, 0, 0);
        acc[0][1] = __builtin_amdgcn_mfma_f32_16x16x32_bf16(B1[c], af[0], acc[0][1], 0, 0, 0);
        acc[1][0] = __builtin_amdgcn_mfma_f32_16x16x32_bf16(B0[c], af[1], acc[1][0], 0, 0, 0);
        acc[1][1] = __builtin_amdgcn_mfma_f32_16x16x32_bf16(B1[c], af[1], acc[1][1], 0, 0, 0);
    }

    // ---- issue B for chunks 4-7 (8 loads; stay in flight across the gate)
#pragma unroll
    for (int c = 0; c < 4; ++c) {
        B0[c] = *(const bf16x8*)(bp + (size_t)(c + 4) * (16 * 512));
        B1[c] = *(const bf16x8*)(bp + (size_t)(c + 4) * (16 * 512) + 512);
    }

    // ---- phase 1 gate: half1 landed (8 young B-loads may be outstanding)
    asm volatile("s_waitcnt vmcnt(8)\n\ts_barrier" ::: "memory");

    // ---- phase 1: chunks 4-7 from LDS half1 ----
#pragma unroll
    for (int c = 0; c < 4; ++c) {
        bf16x8 af[2];
#pragma unroll
        for (int mt = 0; mt < 2; ++mt) {
            const int rr  = mt * 16 + lm;
            const int gg0 = c * 8 + ((q * 2)     ^ (lm & 7));
            const int gg1 = c * 8 + ((q * 2 + 1) ^ (lm & 7));
            const f32x4 lo = *(const f32x4*)((const char*)As + 16384 + rr * 512 + gg0 * 16);
            const f32x4 hi = *(const f32x4*)((const char*)As + 16384 + rr * 512 + gg1 * 16);
            af[mt] = cvt8(lo, hi);
        }
        acc[0][0] = __builtin_amdgcn_mfma_f32_16x16x32_bf16(B0[c], af[0], acc[0][0], 0, 0, 0);
        acc[0][1] = __builtin_amdgcn_mfma_f32_16x16x32_bf16(B1[c], af[0], acc[0][1], 0, 0, 0);
        acc[1][0] = __builtin_amdgcn_mfma_f32_16x16x32_bf16(B0[c], af[1], acc[1][0], 0, 0, 0);
        acc[1][1] = __builtin_amdgcn_mfma_f32_16x16x32_bf16(B1[c], af[1], acc[1][1], 0, 0, 0);
    }

    // ---- epilogue consts (after the pipeline; not live in-loop) ----
    const float p0 = pc[g * 4 + 0], p1 = pc[g * 4 + 1];
    const float p2 = pc[g * 4 + 2], p3 = pc[g * 4 + 3];
    const float q0 = qc[g * 3 + 0], q1 = qc[g * 3 + 1], q2 = qc[g * 3 + 2];

    // ---- epilogue: transposed-C -> lane lm = out-row, reg r = 4 consecutive
    //      cols. ONE NON-TEMPORAL dwordx4 store per (mt,nt): no L2/L3
    //      allocation -> x stays L3-resident, fabric sheds write-allocates.
#pragma unroll
    for (int mt = 0; mt < 2; ++mt) {
        const int row_o = row0 + mt * 16 + lm;
#pragma unroll
        for (int nt = 0; nt < 2; ++nt) {
            const int col0 = g * GOUT_ + wave * 32 + nt * 16 + q * 4;
            const f32x4 bb4 = *(const f32x4*)(bias + col0);
            f32x4 o;
#pragma unroll
            for (int r = 0; r < 4; ++r) {
                const float y   = acc[mt][nt][r] + bb4[r];
                const float num = p0 + y * (p1 + y * (p2 + y * p3));
                const float den = 1.0f + fabsf(y * (q0 + y * (q1 + y * q2)));
                o[r] = num * __builtin_amdgcn_rcpf(den);
            }
            __builtin_nontemporal_store(o, (f32x4*)(out + (size_t)row_o * LDX_ + col0));
        }
    }
}

extern "C" void kernel_launch(void* const* d_in, const int* in_sizes, int n_in,
                              void* d_out, int out_size, void* d_ws, size_t ws_size,
                              hipStream_t stream) {
    const float* x = (const float*)d_in[0];
    const float* W = (const float*)d_in[1];
    const float* b = (const float*)d_in[2];
    const float* p = (const float*)d_in[3];
    const float* q = (const float*)d_in[4];
    float* out = (float*)d_out;

    __hip_bfloat16* Wt = (__hip_bfloat16*)d_ws;   // 1 MiB fragment-tiled bf16 W

    wprep_kernel<<<128, 256, 0, stream>>>(W, Wt);
    gkan_kernel<<<2048, 512, 0, stream>>>(x, Wt, b, p, q, out);
}

// Round 12
// 127.305 us; speedup vs baseline: 1.4758x; 1.0612x over previous
//
#include <hip/hip_runtime.h>
#include <hip/hip_bf16.h>

#define G_ 8
#define GIN_ 256
#define GOUT_ 256
#define NROWS_ 8192
#define LDX_ 2048   // = G_*GIN_ = row stride of x and out

typedef __attribute__((ext_vector_type(4))) float f32x4;
typedef __attribute__((ext_vector_type(8))) short bf16x8;

// ---------------------------------------------------------------------------
// Prep: W [G][GIN=k 256][GOUT=col 256] f32 -> WtB fragment-tiled bf16:
//   granule(g, c, cb, c16, quad) = W[g][k = c*32+quad*8 .. +8][col = cb*16+c16]
//   element offset = g*65536 + (c*16+cb)*512 + c16*32 + quad*8
// A wave's B-frag load (16 cols x 4 quads x 16B) is ONE contiguous 1 KB.
// (unchanged — harness-verified)
// ---------------------------------------------------------------------------
__global__ __launch_bounds__(256) void wprep_kernel(const float* __restrict__ W,
                                                    __hip_bfloat16* __restrict__ Wt) {
    __shared__ float tile[64][65];   // +1 pad
    const int bid = blockIdx.x;
    const int g  = bid >> 4;
    const int kt = (bid >> 2) & 3;   // k-tile (64 wide)
    const int ct = bid & 3;          // col-tile (64 wide)
    const float* Wg = W + g * (GIN_ * GOUT_);
    __hip_bfloat16* Wo = Wt + (size_t)g * (GIN_ * GOUT_);
    const int lane_o = threadIdx.x & 63;   // col within tile
    const int sub    = threadIdx.x >> 6;   // 0..3
#pragma unroll
    for (int r = 0; r < 16; ++r) {
        int i = r * 4 + sub;               // k within tile
        tile[i][lane_o] = Wg[(kt * 64 + i) * GOUT_ + ct * 64 + lane_o];
    }
    __syncthreads();
    const int col = threadIdx.x & 63;
    const int kgb = threadIdx.x >> 6;      // 0..3
#pragma unroll
    for (int h = 0; h < 2; ++h) {
        const int kg    = kgb + h * 4;     // 0..7: granule-of-8k in 64-k tile
        const int kglob = kt * 64 + kg * 8;
        const int c     = kglob >> 5;      // k-chunk 0..7
        const int quad  = (kglob >> 3) & 3;
        const int colg  = ct * 64 + col;
        const int cb    = colg >> 4;
        const int c16   = colg & 15;
        union { __hip_bfloat16 hh[8]; bf16x8 v; } cv;
#pragma unroll
        for (int j = 0; j < 8; ++j)
            cv.hh[j] = __float2bfloat16(tile[kg * 8 + j][col]);
        *(bf16x8*)(Wo + (size_t)(c * 16 + cb) * 512 + c16 * 32 + quad * 8) = cv.v;
    }
}

__device__ __forceinline__ bf16x8 cvt8(const f32x4 a, const f32x4 b) {
    union { __hip_bfloat16 h[8]; bf16x8 v; } u;
    u.h[0] = __float2bfloat16(a.x); u.h[1] = __float2bfloat16(a.y);
    u.h[2] = __float2bfloat16(a.z); u.h[3] = __float2bfloat16(a.w);
    u.h[4] = __float2bfloat16(b.x); u.h[5] = __float2bfloat16(b.y);
    u.h[6] = __float2bfloat16(b.z); u.h[7] = __float2bfloat16(b.w);
    return u.v;
}

// ---------------------------------------------------------------------------
// Main fused kernel — DMA DOUBLE-BUFFERED 4-SLAB PIPELINE (R12).
//  R11's key datum: the same kernel sustained 3.0 TB/s when given more
//  bytes -> 101 MB @ 2.4 TB/s is NOT an HBM service ceiling. Little's law:
//  ~6 TB/s needs ~22 KB/CU of reads continuously in flight; every prior
//  variant held reads in flight only in short bursts (compiler sinks /
//  collapses reg-staged prefetch: VGPR 24-40 observed 3x), or not at all.
//  Fix: reads whose issue position is compiler-proof — global_load_lds
//  (zero dest VGPRs) double-buffered across slabs with counted vmcnt:
//   prologue: DMA slab0 (4 ops) + B-resident (16 loads, 64 VGPR)
//             + bias + p/q; vmcnt(0)+barrier.
//   iter s:   issue DMA slab s+1 -> buf^1 (all waves past the previous
//             barrier => nobody still reads buf^1: race-free);
//             compute slab s (LDS+VALU+MFMA only — zero in-loop vmem,
//             so counting is exact); epilogue s (4 stores);
//             vmcnt(4)+barrier  [<=4 left = stores(s) => DMA(s+1) landed;
//             next slab's 32 KB stays in flight through the barrier].
//  In-flight reads: 32 KB/block x 2 resident blocks = 64 KB/CU continuous.
//  LDS 2x32 KB f32, R7's verified layout+swizzle; R8's swapped-operand
//  MFMA (transposed C) + f32x4 cached stores. Numerics identical.
// Grid: 8 g x 64 rowblocks(128 rows) = 512 blocks; bid&7 = g (Wt L2-local).
// ---------------------------------------------------------------------------
__global__ __launch_bounds__(512, 4) void gkan_kernel(const float* __restrict__ x,
                                                      const __hip_bfloat16* __restrict__ Wt,
                                                      const float* __restrict__ bias,
                                                      const float* __restrict__ pc,
                                                      const float* __restrict__ qc,
                                                      float* __restrict__ out) {
    __shared__ __align__(16) float As[2][32 * 256];   // 2 x 32 KB raw f32 slabs

    const int bid  = blockIdx.x;
    const int g    = bid & 7;
    const int row0 = (bid >> 3) * 128;

    const int t    = threadIdx.x;
    const int wave = t >> 6;             // 0..7 -> cols [wave*32, +32)
    const int lane = t & 63;
    const int lm   = lane & 15;
    const int q    = lane >> 4;

    // DMA staging geometry (R7-verified): round r stages row r*8+wave of the
    // slab; lane l covers 16B-slot l; src granule = (l & ~7)|((l&7)^wave)
    // (inverse swizzle at source; read applies the same XOR).
    const float* xbase = x + (size_t)row0 * LDX_ + g * GIN_;
    const int gsrc = (lane & ~7) | ((lane & 7) ^ wave);

#define DMA_SLAB(s, buf)                                                      \
    {                                                                         \
        const float* xs_ = xbase + (size_t)(s) * 32 * LDX_;                   \
        _Pragma("unroll")                                                     \
        for (int r_ = 0; r_ < 4; ++r_) {                                      \
            const float* src_ = xs_ + (size_t)(r_ * 8 + wave) * LDX_ + gsrc * 4; \
            __builtin_amdgcn_global_load_lds(                                 \
                (const __attribute__((address_space(1))) void*)src_,          \
                (__attribute__((address_space(3))) void*)                     \
                    ((char*)As + (buf) * 32768 + r_ * 8192 + t * 16),         \
                16, 0, 0);                                                    \
        }                                                                     \
    }

    // ---- prologue: DMA slab0; B-resident (16 x contiguous 1 KB from L2);
    //      bias + p/q consts ----
    DMA_SLAB(0, 0);

    const __hip_bfloat16* bp = Wt + (size_t)g * (GIN_ * GOUT_)
                                  + (wave * 2) * 512 + lm * 32 + q * 8;
    bf16x8 B0[8], B1[8];
#pragma unroll
    for (int c = 0; c < 8; ++c) {
        B0[c] = *(const bf16x8*)(bp + (size_t)c * (16 * 512));
        B1[c] = *(const bf16x8*)(bp + (size_t)c * (16 * 512) + 512);
    }

    f32x4 bb4[2];
    int col0[2];
#pragma unroll
    for (int nt = 0; nt < 2; ++nt) {
        col0[nt] = g * GOUT_ + wave * 32 + nt * 16 + q * 4;
        bb4[nt]  = *(const f32x4*)(bias + col0[nt]);
    }
    const float p0 = pc[g * 4 + 0], p1 = pc[g * 4 + 1];
    const float p2 = pc[g * 4 + 2], p3 = pc[g * 4 + 3];
    const float q0 = qc[g * 3 + 0], q1 = qc[g * 3 + 1], q2 = qc[g * 3 + 2];

    // prologue gate: everything above landed
    asm volatile("s_waitcnt vmcnt(0)\n\ts_barrier" ::: "memory");

    // ---- 4-slab pipeline ----
#pragma unroll 1
    for (int s = 0; s < 4; ++s) {
        const int buf = s & 1;

        // issue next slab's DMA into the other buffer (race-free: all waves
        // are past the previous barrier => done reading buf^1)
        if (s < 3) DMA_SLAB(s + 1, buf ^ 1);

        // ---- compute slab s: 8 chunks, zero vmem ----
        f32x4 acc[2][2] = {};   // [mt][nt], swapped-operand (transposed C)
        const char* ab = (const char*)As + buf * 32768;
#pragma unroll
        for (int c = 0; c < 8; ++c) {
            bf16x8 af[2];
#pragma unroll
            for (int mt = 0; mt < 2; ++mt) {
                const int rr  = mt * 16 + lm;
                const int gg0 = c * 8 + ((q * 2)     ^ (lm & 7));
                const int gg1 = c * 8 + ((q * 2 + 1) ^ (lm & 7));
                const f32x4 lo = *(const f32x4*)(ab + rr * 1024 + gg0 * 16);
                const f32x4 hi = *(const f32x4*)(ab + rr * 1024 + gg1 * 16);
                af[mt] = cvt8(lo, hi);
            }
            acc[0][0] = __builtin_amdgcn_mfma_f32_16x16x32_bf16(B0[c], af[0], acc[0][0], 0, 0, 0);
            acc[0][1] = __builtin_amdgcn_mfma_f32_16x16x32_bf16(B1[c], af[0], acc[0][1], 0, 0, 0);
            acc[1][0] = __builtin_amdgcn_mfma_f32_16x16x32_bf16(B0[c], af[1], acc[1][0], 0, 0, 0);
            acc[1][1] = __builtin_amdgcn_mfma_f32_16x16x32_bf16(B1[c], af[1], acc[1][1], 0, 0, 0);
        }

        // ---- epilogue slab s: transposed-C (lane lm = out-row, reg r = 4
        //      consecutive cols), bias + rational, f32x4 cached stores ----
#pragma unroll
        for (int mt = 0; mt < 2; ++mt) {
            const int row_o = row0 + s * 32 + mt * 16 + lm;
#pragma unroll
            for (int nt = 0; nt < 2; ++nt) {
                f32x4 o;
#pragma unroll
                for (int r = 0; r < 4; ++r) {
                    const float y   = acc[mt][nt][r] + bb4[nt][r];
                    const float num = p0 + y * (p1 + y * (p2 + y * p3));
                    const float den = 1.0f + fabsf(y * (q0 + y * (q1 + y * q2)));
                    o[r] = num * __builtin_amdgcn_rcpf(den);
                }
                *(f32x4*)(out + (size_t)row_o * LDX_ + col0[nt]) = o;
            }
        }

        // ---- slab gate: <=4 vmem left (= this slab's stores) => DMA(s+1)
        //      landed; next slab's reads stay in flight through the barrier.
        if (s < 3)
            asm volatile("s_waitcnt vmcnt(4)\n\ts_barrier" ::: "memory");
    }
#undef DMA_SLAB
}

extern "C" void kernel_launch(void* const* d_in, const int* in_sizes, int n_in,
                              void* d_out, int out_size, void* d_ws, size_t ws_size,
                              hipStream_t stream) {
    const float* x = (const float*)d_in[0];
    const float* W = (const float*)d_in[1];
    const float* b = (const float*)d_in[2];
    const float* p = (const float*)d_in[3];
    const float* q = (const float*)d_in[4];
    float* out = (float*)d_out;

    __hip_bfloat16* Wt = (__hip_bfloat16*)d_ws;   // 1 MiB fragment-tiled bf16 W

    wprep_kernel<<<128, 256, 0, stream>>>(W, Wt);
    gkan_kernel<<<512, 512, 0, stream>>>(x, Wt, b, p, q, out);
}